// Round 5
// baseline (1018.415 us; speedup 1.0000x reference)
//
#include <hip/hip_runtime.h>
#include <math.h>

// ---------------- problem constants ----------------
#define N_   32
#define NUP_ 16
#define M_   4
#define D_   128
#define K_   64
#define F_   32
#define H_   45
#define L_   3
#define LOG2_ 0.69314718055994530942f

typedef __attribute__((ext_vector_type(8))) short short8;
typedef __attribute__((ext_vector_type(4))) float float4v;

__device__ __forceinline__ float ssp(float v) {
    return __logf(1.0f + __expf(v)) - LOG2_;   // ssp(0)==0 exactly
}

__device__ __forceinline__ unsigned short f2bf(float x) {   // RTNE, prep only
    unsigned int u = __float_as_uint(x);
    return (unsigned short)((u + 0x7FFFu + ((u >> 16) & 1u)) >> 16);
}

// pack two floats -> bf16x2 (round-half-up)
__device__ __forceinline__ unsigned int pkbf(float x, float y) {
    return __builtin_amdgcn_perm(__float_as_uint(y) + 0x8000u,
                                 __float_as_uint(x) + 0x8000u, 0x07060302u);
}

// ---------------- prep: pack weights into MFMA B-fragment order ----------------
// w1B[lc][nt:3][512]        k=(lane>>4)*8+jj (f), n=nt*16+(lane&15) (hidden)
// w2B[lc][ks:2][nt:4][512]  k=p (hidden position 4*l16+nt), p==3 -> bias row
// gB [l][ks:6][nt:8][512]   k=c*64+kk, n=d
// hB [li:2][ks:4][nt:4][512] k=d (identity), n=kout  (hW layers 1,2)
// gbs[l][128] = sum_c gb[l][c][:]
__global__ __launch_bounds__(256) void prep_kernel(
    const float* __restrict__ wW1, const float* __restrict__ wW2,
    const float* __restrict__ wb2, const float* __restrict__ gW,
    const float* __restrict__ hW,  const float* __restrict__ gb,
    short* __restrict__ w1B, short* __restrict__ w2B,
    short* __restrict__ gB,  short* __restrict__ hB, float* __restrict__ gbs)
{
    int blk = blockIdx.x;
    int t = threadIdx.x;
    if (blk < 27) {                       // w1B
        int lc = blk / 3, nt = blk % 3;
        short* dst = w1B + (size_t)blk * 512;
        for (int idx = t; idx < 512; idx += 256) {
            int lane = idx >> 3, jj = idx & 7;
            int k = ((lane >> 4) << 3) + jj;
            int n = nt * 16 + (lane & 15);
            float v = (n < H_) ? wW1[((size_t)lc * H_ + n) * F_ + k] : 0.0f;
            dst[idx] = (short)f2bf(v);
        }
    } else if (blk < 99) {                // w2B
        int b3 = blk - 27;
        int lc = b3 >> 3, rem = b3 & 7, ks = rem >> 2, nt = rem & 3;
        short* dst = w2B + (size_t)b3 * 512;
        for (int idx = t; idx < 512; idx += 256) {
            int lane = idx >> 3, jj = idx & 7;
            int p = ks * 32 + ((lane >> 4) << 3) + jj;
            int n = nt * 16 + (lane & 15);
            float v;
            if (p == 3) v = wb2[(size_t)lc * K_ + n];
            else if ((p & 3) < 3) {
                int u = (p & 3) * 16 + (p >> 2);
                v = (u < H_) ? wW2[((size_t)lc * K_ + n) * H_ + u] : 0.0f;
            } else v = 0.0f;
            dst[idx] = (short)f2bf(v);
        }
    } else if (blk < 243) {               // gB
        int g = blk - 99;
        int l = g / 48, rem = g % 48;
        short* dst = gB + (size_t)g * 512;
        for (int idx = t; idx < 512; idx += 256) {
            int lane = idx >> 3, jj = idx & 7;
            int k = (rem >> 3) * 32 + ((lane >> 4) << 3) + jj;
            int c = k >> 6, kk = k & 63;
            int n = ((rem & 7) * 16) + (lane & 15);
            dst[idx] = (short)f2bf(gW[(((size_t)l * 3 + c) * D_ + n) * K_ + kk]);
        }
    } else if (blk < 275) {               // hB (identity d-order)
        int hh = blk - 243;
        int li = hh >> 4, rem = hh & 15;
        short* dst = hB + (size_t)hh * 512;
        for (int idx = t; idx < 512; idx += 256) {
            int lane = idx >> 3, jj = idx & 7;
            int d = (rem >> 2) * 32 + ((lane >> 4) << 3) + jj;   // 0..127
            int n = ((rem & 3) * 16) + (lane & 15);
            dst[idx] = (short)f2bf(hW[(((size_t)(li + 1)) * K_ + n) * D_ + d]);
        }
    } else {                              // gbs
        for (int idx = t; idx < 384; idx += 256) {
            int l = idx >> 7, d = idx & 127;
            gbs[idx] = gb[((size_t)l * 3 + 0) * D_ + d]
                     + gb[((size_t)l * 3 + 1) * D_ + d]
                     + gb[((size_t)l * 3 + 2) * D_ + d];
        }
    }
}

// ---------------- h0 ----------------
__global__ __launch_bounds__(64) void h0_kernel(
    const float* __restrict__ X, const float* __restrict__ hW,
    const float* __restrict__ hb, float* __restrict__ h0)
{
    int k = threadIdx.x;
    float a = hb[k];
    const float* w = hW + (size_t)k * D_;
    #pragma unroll 8
    for (int dd = 0; dd < D_; ++dd) a += w[dd] * X[dd];
    h0[k] = a;
}

// ---------------- MFMA edge kernel: one block = one b; wave = 4 same-spin i's ----------------
#define HDS 72
__global__ __launch_bounds__(512, 6) void edge_kernel(
    const float* __restrict__ ee, const float* __restrict__ en,
    const float* __restrict__ Y,
    const short* __restrict__ w1B, const float* __restrict__ wb1,
    const short* __restrict__ w2B,
    const float* __restrict__ h, const float* __restrict__ h0,
    unsigned short* __restrict__ zb, int l, int hmode)
{
    __shared__ float wrowT[32 * 64];     // 8192 B, [j][l16*4+m] = h[j][m*16+l16]
    __shared__ float yT[16 * 20];        // 1280 B, [l16][nt*4+r] = Y[r][nt*16+l16]
    __shared__ short hd_s[8][16 * HDS];  // 18432 B

    const int tid  = threadIdx.x;
    const int wv   = tid >> 6;
    const int lane = tid & 63;
    const int quad = lane >> 4;
    const int l16  = lane & 15;
    const int b    = blockIdx.x;

    // ---- stage wrowT (once per b) ----
    {
        int row = tid >> 4;
        int c0 = (tid & 15) * 4;
        const float* src = hmode ? (h + ((size_t)(b * N_ + row)) * K_ + c0) : (h0 + c0);
        float4 v = *(const float4*)src;
        wrowT[row * 64 + ((c0 + 0) & 15) * 4 + ((c0 + 0) >> 4)] = v.x;
        wrowT[row * 64 + ((c0 + 1) & 15) * 4 + ((c0 + 1) >> 4)] = v.y;
        wrowT[row * 64 + ((c0 + 2) & 15) * 4 + ((c0 + 2) >> 4)] = v.z;
        wrowT[row * 64 + ((c0 + 3) & 15) * 4 + ((c0 + 3) >> 4)] = v.w;
        if (tid < 64) {
            int yl = tid & 15, g = tid >> 4;
            float4 yv;
            yv.x = Y[0 * K_ + g * 16 + yl];
            yv.y = Y[1 * K_ + g * 16 + yl];
            yv.z = Y[2 * K_ + g * 16 + yl];
            yv.w = Y[3 * K_ + g * 16 + yl];
            *(float4*)(yT + yl * 20 + g * 4) = yv;
        }
    }
    __syncthreads();

    const int i0  = wv * 4;
    const int cA  = (wv < 4) ? 0 : 1;
    const int lc0 = l * 3 + cA;
    const int lc1 = l * 3 + 1 - cA;
    const int lc2 = l * 3 + 2;
    short* hd = hd_s[wv];
    const unsigned int cpad = (l16 == 0) ? 0x3F808000u : 0u;  // bf16 1.0 in bias slot

    // stage-1 biases, once per wave (b1r[t*3+nt], t = channel slot {cA,1-cA,2})
    float b1r[9];
    {
        const int lcs[3] = {lc0, lc1, lc2};
        #pragma unroll
        for (int t = 0; t < 3; ++t)
            #pragma unroll
            for (int nt = 0; nt < 3; ++nt) {
                int col = nt * 16 + l16;
                b1r[t * 3 + nt] = (col < H_) ? wb1[(size_t)lcs[t] * H_ + col] : 0.0f;
            }
    }

    // ---- 4 electronic i's, 2 elec tiles each ----
    for (int ii = 0; ii < 4; ++ii) {
        const int i = i0 + ii;
        const size_t bi = (size_t)b * N_ + i;

        const float* ep = ee + (bi * N_ + l16) * F_ + quad * 8;
        float4 e0a = *(const float4*)(ep);
        float4 e0b = *(const float4*)(ep + 4);
        float4 e1a = *(const float4*)(ep + 16 * F_);
        float4 e1b = *(const float4*)(ep + 16 * F_ + 4);
        union { short8 s; unsigned int u[4]; } A[2];
        A[0].u[0] = pkbf(e0a.x, e0a.y); A[0].u[1] = pkbf(e0a.z, e0a.w);
        A[0].u[2] = pkbf(e0b.x, e0b.y); A[0].u[3] = pkbf(e0b.z, e0b.w);
        A[1].u[0] = pkbf(e1a.x, e1a.y); A[1].u[1] = pkbf(e1a.z, e1a.w);
        A[1].u[2] = pkbf(e1b.x, e1b.y); A[1].u[3] = pkbf(e1b.z, e1b.w);

        const int lct[2] = {lc0, lc1};
        const int dtile = i >> 4;         // tile holding the diagonal row

        #pragma unroll
        for (int t = 0; t < 2; ++t) {
            const int lc = lct[t];

            // stage 1
            float4v acc1[3];
            #pragma unroll
            for (int nt = 0; nt < 3; ++nt) {
                float b1c = b1r[t * 3 + nt];
                acc1[nt] = (float4v){b1c, b1c, b1c, b1c};
                short8 bf = *(const short8*)(w1B + (((size_t)lc * 3 + nt) << 9) + (lane << 3));
                acc1[nt] = __builtin_amdgcn_mfma_f32_16x16x32_bf16(A[t].s, bf, acc1[nt], 0, 0, 0);
            }

            // ssp + hd write; zero diagonal row (incl. bias slot) -> C row exactly 0
            const int drow = (t == dtile) ? (i & 15) : 99;
            #pragma unroll
            for (int r = 0; r < 4; ++r) {
                float s0 = ssp(acc1[0][r]);
                float s1 = ssp(acc1[1][r]);
                float s2 = ssp(acc1[2][r]);
                unsigned int lo = pkbf(s0, s1);
                unsigned int hi = __builtin_amdgcn_perm(cpad, __float_as_uint(s2) + 0x8000u, 0x07060302u);
                if (quad * 4 + r == drow) { lo = 0u; hi = 0u; }
                uint2 pr; pr.x = lo; pr.y = hi;
                *(uint2*)(hd + (quad * 4 + r) * HDS + 4 * l16) = pr;
            }

            // stage 2
            float4v acc2[4];
            #pragma unroll
            for (int nt = 0; nt < 4; ++nt) acc2[nt] = (float4v){0.f, 0.f, 0.f, 0.f};
            #pragma unroll
            for (int ks = 0; ks < 2; ++ks) {
                short8 a2 = *(const short8*)(hd + l16 * HDS + ks * 32 + quad * 8);
                #pragma unroll
                for (int nt = 0; nt < 4; ++nt) {
                    short8 bf = *(const short8*)(w2B + ((((size_t)lc * 2 + ks) * 4 + nt) << 9) + (lane << 3));
                    acc2[nt] = __builtin_amdgcn_mfma_f32_16x16x32_bf16(a2, bf, acc2[nt], 0, 0, 0);
                }
            }

            // epilogue: pure fma (diag row already zero)
            float p0 = 0.f, p1 = 0.f, p2 = 0.f, p3 = 0.f;
            #pragma unroll
            for (int r = 0; r < 4; ++r) {
                int jrow = t * 16 + quad * 4 + r;
                float4 wv4 = *(const float4*)(wrowT + jrow * 64 + l16 * 4);
                p0 += acc2[0][r] * wv4.x;
                p1 += acc2[1][r] * wv4.y;
                p2 += acc2[2][r] * wv4.z;
                p3 += acc2[3][r] * wv4.w;
            }
            p0 += __shfl_xor(p0, 16); p0 += __shfl_xor(p0, 32);
            p1 += __shfl_xor(p1, 16); p1 += __shfl_xor(p1, 32);
            p2 += __shfl_xor(p2, 16); p2 += __shfl_xor(p2, 32);
            p3 += __shfl_xor(p3, 16); p3 += __shfl_xor(p3, 32);
            float v = p0;
            v = (quad == 1) ? p1 : v;
            v = (quad == 2) ? p2 : v;
            v = (quad == 3) ? p3 : v;
            const int cch = (t == 0) ? cA : 1 - cA;
            zb[bi * 192 + cch * 64 + lane] =
                (unsigned short)((__float_as_uint(v) + 0x8000u) >> 16);
        }
    }

    // ---- nuc: 4 i's x 4 m packed into ONE 16-row tile ----
    {
        const float* np = en + (((size_t)b * N_ + i0 + (l16 >> 2)) * M_ + (l16 & 3)) * F_ + quad * 8;
        float4 na = *(const float4*)(np);
        float4 nb = *(const float4*)(np + 4);
        union { short8 s; unsigned int u[4]; } An;
        An.u[0] = pkbf(na.x, na.y); An.u[1] = pkbf(na.z, na.w);
        An.u[2] = pkbf(nb.x, nb.y); An.u[3] = pkbf(nb.z, nb.w);

        float4v acc1[3];
        #pragma unroll
        for (int nt = 0; nt < 3; ++nt) {
            float b1c = b1r[6 + nt];
            acc1[nt] = (float4v){b1c, b1c, b1c, b1c};
            short8 bf = *(const short8*)(w1B + (((size_t)lc2 * 3 + nt) << 9) + (lane << 3));
            acc1[nt] = __builtin_amdgcn_mfma_f32_16x16x32_bf16(An.s, bf, acc1[nt], 0, 0, 0);
        }
        #pragma unroll
        for (int r = 0; r < 4; ++r) {
            float s0 = ssp(acc1[0][r]);
            float s1 = ssp(acc1[1][r]);
            float s2 = ssp(acc1[2][r]);
            unsigned int lo = pkbf(s0, s1);
            unsigned int hi = __builtin_amdgcn_perm(cpad, __float_as_uint(s2) + 0x8000u, 0x07060302u);
            uint2 pr; pr.x = lo; pr.y = hi;
            *(uint2*)(hd + (quad * 4 + r) * HDS + 4 * l16) = pr;
        }
        float4v acc2[4];
        #pragma unroll
        for (int nt = 0; nt < 4; ++nt) acc2[nt] = (float4v){0.f, 0.f, 0.f, 0.f};
        #pragma unroll
        for (int ks = 0; ks < 2; ++ks) {
            short8 a2 = *(const short8*)(hd + l16 * HDS + ks * 32 + quad * 8);
            #pragma unroll
            for (int nt = 0; nt < 4; ++nt) {
                short8 bf = *(const short8*)(w2B + ((((size_t)lc2 * 2 + ks) * 4 + nt) << 9) + (lane << 3));
                acc2[nt] = __builtin_amdgcn_mfma_f32_16x16x32_bf16(a2, bf, acc2[nt], 0, 0, 0);
            }
        }
        // rows quad*4+r = (i0+quad)'s nuc row m=r; z_nuc[k] = sum_m o*Y[m,k]
        size_t zbase = ((size_t)b * N_ + i0 + quad) * 192 + 128 + l16;
        #pragma unroll
        for (int nt = 0; nt < 4; ++nt) {
            float4 yv = *(const float4*)(yT + l16 * 20 + nt * 4);
            float p = acc2[nt][0] * yv.x + acc2[nt][1] * yv.y
                    + acc2[nt][2] * yv.z + acc2[nt][3] * yv.w;
            zb[zbase + nt * 16] = (unsigned short)((__float_as_uint(p) + 0x8000u) >> 16);
        }
    }
}

// ---------------- MFMA fuse: block = 32 rows, 4 waves = (row-tile x nt-half) ----------------
#define HXS2 136
__global__ __launch_bounds__(256) void fuse_kernel(
    const unsigned short* __restrict__ zb, const short* __restrict__ gB,
    const float* __restrict__ gbs, const float* __restrict__ X,
    const short* __restrict__ hB, const float* __restrict__ hb,
    float* __restrict__ xout, float* __restrict__ hout,
    int l, int first, int compute_h)
{
    __shared__ short hx[32 * HXS2];    // 8704 B

    const int tid  = threadIdx.x;
    const int wvv  = tid >> 6;
    const int r2   = wvv & 1;          // row-tile
    const int nh   = wvv >> 1;         // nt-half
    const int lane = tid & 63;
    const int quad = lane >> 4;
    const int l16  = lane & 15;
    const int row0 = blockIdx.x * 32 + r2 * 16;

    // ---- Z @ G^T : 6 K-steps x 4 column tiles (this wave's nt-half) ----
    float4v acc[4];
    #pragma unroll
    for (int n = 0; n < 4; ++n) acc[n] = (float4v){0.f, 0.f, 0.f, 0.f};
    const short* zrow = (const short*)zb + (size_t)(row0 + l16) * 192;
    const short* gl = gB + (size_t)l * 48 * 512;
    #pragma unroll
    for (int ks = 0; ks < 6; ++ks) {
        short8 az = *(const short8*)(zrow + ks * 32 + quad * 8);
        #pragma unroll
        for (int n = 0; n < 4; ++n) {
            short8 bf = *(const short8*)(gl + ((size_t)(ks * 8 + nh * 4 + n) << 9) + (lane << 3));
            acc[n] = __builtin_amdgcn_mfma_f32_16x16x32_bf16(az, bf, acc[n], 0, 0, 0);
        }
    }

    // ---- epilogue: residual + bias, store x, pack hx ----
    #pragma unroll
    for (int n = 0; n < 4; ++n) {
        int col = (nh * 4 + n) * 16 + l16;
        float gv = gbs[(size_t)l * D_ + col];
        float xbc = first ? X[col] : 0.0f;
        #pragma unroll
        for (int r = 0; r < 4; ++r) {
            size_t gi = (size_t)(row0 + quad * 4 + r) * D_ + col;
            float xo = (first ? xbc : xout[gi]) + gv + acc[n][r];
            xout[gi] = xo;
            if (compute_h)
                hx[(r2 * 16 + quad * 4 + r) * HXS2 + col] =
                    (short)((__float_as_uint(xo) + 0x8000u) >> 16);
        }
    }
    if (!compute_h) return;
    __syncthreads();

    // ---- h_next = x @ hW^T : 4 K-steps x 2 column tiles ----
    float4v ah[2];
    ah[0] = (float4v){0.f, 0.f, 0.f, 0.f};
    ah[1] = (float4v){0.f, 0.f, 0.f, 0.f};
    const short* hl = hB + (size_t)l * 16 * 512;
    #pragma unroll
    for (int ks = 0; ks < 4; ++ks) {
        short8 a = *(const short8*)(hx + (r2 * 16 + l16) * HXS2 + ks * 32 + quad * 8);
        #pragma unroll
        for (int n = 0; n < 2; ++n) {
            short8 bf = *(const short8*)(hl + ((size_t)(ks * 4 + nh * 2 + n) << 9) + (lane << 3));
            ah[n] = __builtin_amdgcn_mfma_f32_16x16x32_bf16(a, bf, ah[n], 0, 0, 0);
        }
    }
    #pragma unroll
    for (int n = 0; n < 2; ++n) {
        int kc = (nh * 2 + n) * 16 + l16;
        float hbv = hb[((size_t)(l + 1)) * K_ + kc];
        #pragma unroll
        for (int r = 0; r < 4; ++r)
            hout[(size_t)(row0 + quad * 4 + r) * K_ + kc] = ah[n][r] + hbv;
    }
}

// ---------------- launch ----------------
extern "C" void kernel_launch(void* const* d_in, const int* in_sizes, int n_in,
                              void* d_out, int out_size, void* d_ws, size_t ws_size,
                              hipStream_t stream)
{
    const float* ee  = (const float*)d_in[0];
    const float* en  = (const float*)d_in[1];
    const float* X   = (const float*)d_in[2];
    const float* Y   = (const float*)d_in[3];
    const float* wW1 = (const float*)d_in[4];
    const float* wb1 = (const float*)d_in[5];
    const float* wW2 = (const float*)d_in[6];
    const float* wb2 = (const float*)d_in[7];
    const float* hW  = (const float*)d_in[8];
    const float* hb  = (const float*)d_in[9];
    const float* gW  = (const float*)d_in[10];
    const float* gb  = (const float*)d_in[11];
    float* xout = (float*)d_out;

    // workspace carve (all 16B-aligned)
    char* ws = (char*)d_ws;
    float*          h   = (float*)(ws);                         // 8,388,608 B
    unsigned short* zb  = (unsigned short*)(ws + 8388608);      // 12,582,912 B
    float*          h0  = (float*)(ws + 8388608 + 12582912);    // 256 B
    short*          w1B = (short*)(ws + 20971520 + 256);        // 27,648 B
    short*          w2B = w1B + (size_t)27 * 512;               // 73,728 B
    short*          gB  = w2B + (size_t)72 * 512;               // 147,456 B
    short*          hB  = gB  + (size_t)144 * 512;              // 32,768 B
    float*          gbs = (float*)(hB + (size_t)32 * 512);      // 1,536 B

    prep_kernel<<<276, 256, 0, stream>>>(wW1, wW2, wb2, gW, hW, gb,
                                         w1B, w2B, gB, hB, gbs);
    h0_kernel<<<1, 64, 0, stream>>>(X, hW, hb, h0);

    // layer 0
    edge_kernel<<<1024, 512, 0, stream>>>(ee, en, Y, w1B, wb1, w2B, h, h0, zb, 0, 0);
    fuse_kernel<<<1024, 256, 0, stream>>>(zb, gB, gbs, X, hB, hb, xout, h, 0, 1, 1);
    // layer 1
    edge_kernel<<<1024, 512, 0, stream>>>(ee, en, Y, w1B, wb1, w2B, h, h0, zb, 1, 1);
    fuse_kernel<<<1024, 256, 0, stream>>>(zb, gB, gbs, X, hB, hb, xout, h, 1, 0, 1);
    // layer 2
    edge_kernel<<<1024, 512, 0, stream>>>(ee, en, Y, w1B, wb1, w2B, h, h0, zb, 2, 1);
    fuse_kernel<<<1024, 256, 0, stream>>>(zb, gB, gbs, X, hB, hb, xout, h, 2, 0, 0);
}